// Round 1
// baseline (556.291 us; speedup 1.0000x reference)
//
#include <hip/hip_runtime.h>

// Streaming masked-|diff| mean over N=20M rows x 5 fp32 cols.
// Memory-bound: 480 MB read -> roofline ~76 us @ 6.3 TB/s.
// Stage 1: grid-stride, 4 rows/thread via 5x float4 loads, block partials -> d_ws.
// Stage 2: single block reduces partials, writes mean to d_out[0].

#define NBLOCKS 2048
#define NTHREADS 256

__device__ __forceinline__ float row_term(float c0, float c2, float c4, float tgt) {
    float d = (fabsf(c4 - c2) < 0.1f) ? (c0 - c4) : (c0 - tgt);
    return fabsf(d);
}

__global__ __launch_bounds__(NTHREADS) void loss_partial(
    const float* __restrict__ in, const float* __restrict__ tg,
    float* __restrict__ partial, long long nrows)
{
    const long long ngroups = nrows >> 2;  // groups of 4 rows = 20 floats = 5 float4
    const long long tid = (long long)blockIdx.x * blockDim.x + threadIdx.x;
    const long long stride = (long long)gridDim.x * blockDim.x;
    const float4* __restrict__ in4 = (const float4*)in;
    const float4* __restrict__ tg4 = (const float4*)tg;

    float sum = 0.0f;
    for (long long g = tid; g < ngroups; g += stride) {
        const float4 v0 = in4[5 * g + 0];  // r0: c0 c1 c2 c3
        const float4 v1 = in4[5 * g + 1];  // r0: c4 | r1: c0 c1 c2
        const float4 v2 = in4[5 * g + 2];  // r1: c3 c4 | r2: c0 c1
        const float4 v3 = in4[5 * g + 3];  // r2: c2 c3 c4 | r3: c0
        const float4 v4 = in4[5 * g + 4];  // r3: c1 c2 c3 c4
        const float4 t  = tg4[g];

        sum += row_term(v0.x, v0.z, v1.x, t.x);  // row 0
        sum += row_term(v1.y, v1.w, v2.y, t.y);  // row 1
        sum += row_term(v2.z, v3.x, v3.z, t.z);  // row 2
        sum += row_term(v3.w, v4.y, v4.w, t.w);  // row 3
    }

    // tail rows (nrows not divisible by 4)
    for (long long r = (ngroups << 2) + tid; r < nrows; r += stride) {
        sum += row_term(in[5 * r + 0], in[5 * r + 2], in[5 * r + 4], tg[r]);
    }

    // wave64 reduce
    #pragma unroll
    for (int off = 32; off > 0; off >>= 1)
        sum += __shfl_down(sum, off, 64);

    __shared__ float wsum[NTHREADS / 64];
    const int lane = threadIdx.x & 63;
    const int wave = threadIdx.x >> 6;
    if (lane == 0) wsum[wave] = sum;
    __syncthreads();
    if (threadIdx.x == 0) {
        float s = 0.0f;
        #pragma unroll
        for (int w = 0; w < NTHREADS / 64; ++w) s += wsum[w];
        partial[blockIdx.x] = s;
    }
}

__global__ __launch_bounds__(NTHREADS) void loss_final(
    const float* __restrict__ partial, int nparts,
    float* __restrict__ out, long long nrows)
{
    float sum = 0.0f;
    for (int i = threadIdx.x; i < nparts; i += NTHREADS) sum += partial[i];

    #pragma unroll
    for (int off = 32; off > 0; off >>= 1)
        sum += __shfl_down(sum, off, 64);

    __shared__ float wsum[NTHREADS / 64];
    const int lane = threadIdx.x & 63;
    const int wave = threadIdx.x >> 6;
    if (lane == 0) wsum[wave] = sum;
    __syncthreads();
    if (threadIdx.x == 0) {
        float s = 0.0f;
        #pragma unroll
        for (int w = 0; w < NTHREADS / 64; ++w) s += wsum[w];
        out[0] = s / (float)nrows;
    }
}

extern "C" void kernel_launch(void* const* d_in, const int* in_sizes, int n_in,
                              void* d_out, int out_size, void* d_ws, size_t ws_size,
                              hipStream_t stream) {
    const float* inputs  = (const float*)d_in[0];
    const float* targets = (const float*)d_in[1];
    float* out = (float*)d_out;
    float* partial = (float*)d_ws;  // NBLOCKS floats

    const long long nrows = (long long)in_sizes[0] / 5;

    loss_partial<<<NBLOCKS, NTHREADS, 0, stream>>>(inputs, targets, partial, nrows);
    loss_final<<<1, NTHREADS, 0, stream>>>(partial, NBLOCKS, out, nrows);
}